// Round 1
// baseline (340.660 us; speedup 1.0000x reference)
//
#include <hip/hip_runtime.h>

// VanillaRNN: S=512, I=1, H=256, C=10, B=2048, fp32 in/out.
// R7: BN 16 -> 8, grid 128 -> 256 blocks (all CUs busy; was 50% idle).
// Rationale: LDS-read pipe was the bottleneck (8 waves x 8KB redundant
// h re-read/step = 64KB/step/CU + 336 conflict-cyc/step). With BN=8,
// lanes n16>=8 broadcast-read the same addresses as n16-8 (free), halving
// unique LDS traffic to 32KB/step/CU; the XOR swizzle is now perfectly
// bank-even (4 rows per 4-bank group per b128). MFMA N-slot half-wasted,
// but MFMA pipe had 8x headroom (~155 of 1360 cyc/step).
// Also: acc chain split 8 -> 2x4 (cut dependent-MFMA latency), xs pitch
// padded to 9 (coprime 32 banks; was 32-way staging conflicts), hT writes
// masked to n16<8.
// 128 blocks x 8 waves structure otherwise as R6: x folded into MFMA C,
// x prefetched 1 step ahead, hT XOR-swizzled (chunk c of row n at c^n),
// weights pre-scaled by 2*log2e: tanh = 1 - 2*rcp(exp2(s)+1).

#define SEQ    512
#define HID    256
#define NCLS   10
#define BN     8      // batch per block
#define NT     512    // 8 waves
#define XPITCH 9      // xs row pitch (coprime with 32 banks)

typedef _Float16 f16x8 __attribute__((ext_vector_type(8)));
typedef _Float16 f16x4 __attribute__((ext_vector_type(4)));
typedef float    f32x4 __attribute__((ext_vector_type(4)));

__global__ __launch_bounds__(NT)
__attribute__((amdgpu_waves_per_eu(2, 2)))
void rnn_mfma(
    const float* __restrict__ x,     // [B, S]
    const float* __restrict__ W_hx,  // [H]
    const float* __restrict__ W_hh,  // [H, H]
    const float* __restrict__ W_ph,  // [C, H]
    const float* __restrict__ b_h,   // [H]
    const float* __restrict__ b_p,   // [C]
    float* __restrict__ out)         // [B, C]
{
    // hT[buf][n][k]: k-chunk c (8 f16) of row n stored at physical chunk c ^ n
    __shared__ __align__(16) _Float16 hT[2][BN][HID];     // 8 KB
    __shared__ __align__(16) float xs[SEQ + 2][XPITCH];   // 18.5 KB

    const int tid  = threadIdx.x;
    const int lane = tid & 63;
    const int wave = tid >> 6;       // 0..7
    const int n16  = lane & 15;
    const int quad = lane >> 4;      // 0..3
    const int nb   = n16 & 7;        // batch col; n16>=8 broadcasts n16-8
    const int b0   = blockIdx.x * BN;

    const float SC = 2.885390081777926814f;   // 2*log2(e)

    // ---- A-frags: rows [wave*32, wave*32+32), pre-scaled by SC, f16 ----
    // A[m = n16][k = quad*8 + j]
    f16x8 afrag[2][8];
#pragma unroll
    for (int mt = 0; mt < 2; ++mt) {
        const int row = wave * 32 + mt * 16 + n16;
#pragma unroll
        for (int ks = 0; ks < 8; ++ks) {
            const float4* p = (const float4*)&W_hh[row * HID + ks * 32 + quad * 8];
            float4 u = p[0], v = p[1];
            f16x8 a;
            a[0] = (_Float16)(SC * u.x); a[1] = (_Float16)(SC * u.y);
            a[2] = (_Float16)(SC * u.z); a[3] = (_Float16)(SC * u.w);
            a[4] = (_Float16)(SC * v.x); a[5] = (_Float16)(SC * v.y);
            a[6] = (_Float16)(SC * v.z); a[7] = (_Float16)(SC * v.w);
            afrag[mt][ks] = a;
        }
    }
    // D rows for this lane: row = wave*32 + mt*16 + quad*4 + r
    f32x4 bias[2], wxv[2];
#pragma unroll
    for (int mt = 0; mt < 2; ++mt)
#pragma unroll
        for (int r = 0; r < 4; ++r) {
            const int row = wave * 32 + mt * 16 + quad * 4 + r;
            bias[mt][r] = SC * b_h[row];
            wxv[mt][r]  = SC * W_hx[row];
        }

    // ---- precomputed swizzled byte offsets (within one buffer) ----
    int roff[8], woff[2];
#pragma unroll
    for (int ks = 0; ks < 8; ++ks)
        roff[ks] = (nb * HID + (((4 * ks + quad) ^ nb) << 3)) * 2;
#pragma unroll
    for (int mt = 0; mt < 2; ++mt)
        woff[mt] = (nb * HID +
                    (((4 * wave + 2 * mt + (quad >> 1)) ^ nb) << 3) +
                    (quad & 1) * 4) * 2;

    // ---- stage xs[t][n] = x[b0+n][t] (pitch 9 -> conflict-light) ----
    for (int i = tid; i < BN * SEQ / 4; i += NT) {
        const int n = i >> 7, t4 = (i & 127) * 4;
        float4 v = *(const float4*)&x[(b0 + n) * SEQ + t4];
        xs[t4 + 0][n] = v.x; xs[t4 + 1][n] = v.y;
        xs[t4 + 2][n] = v.z; xs[t4 + 3][n] = v.w;
    }
    // ---- h0 = 0 (buffer 0 only; buffer 1 fully written each odd step) ----
    for (int i = tid; i < BN * HID / 2; i += NT) ((float*)hT[0])[i] = 0.0f;
    __syncthreads();

    float xv = xs[0][nb];   // prefetched x_t for step 0

#define RNN_STEP(T, RD, WR)                                                   \
    {                                                                         \
        const float xnxt = xs[(T) + 1][nb];  /* prefetch next step's x */     \
        const char* hb = (const char*)hT[RD];                                 \
        f16x8 bfr[8];                                                         \
        _Pragma("unroll")                                                     \
        for (int ks = 0; ks < 8; ++ks)                                        \
            bfr[ks] = *(const f16x8*)(hb + roff[ks]);                         \
        f32x4 acc0[2], acc1[2];                                               \
        _Pragma("unroll")                                                     \
        for (int mt = 0; mt < 2; ++mt) {                                      \
            f32x4 c0;                                                         \
            _Pragma("unroll")                                                 \
            for (int r = 0; r < 4; ++r)                                       \
                c0[r] = fmaf(wxv[mt][r], xv, bias[mt][r]);                    \
            acc0[mt] = __builtin_amdgcn_mfma_f32_16x16x32_f16(                \
                afrag[mt][0], bfr[0], c0, 0, 0, 0);                           \
            acc1[mt] = __builtin_amdgcn_mfma_f32_16x16x32_f16(                \
                afrag[mt][1], bfr[1], (f32x4)0.0f, 0, 0, 0);                  \
        }                                                                     \
        _Pragma("unroll")                                                     \
        for (int ks = 2; ks < 8; ks += 2)                                     \
            _Pragma("unroll")                                                 \
            for (int mt = 0; mt < 2; ++mt) {                                  \
                acc0[mt] = __builtin_amdgcn_mfma_f32_16x16x32_f16(            \
                    afrag[mt][ks], bfr[ks], acc0[mt], 0, 0, 0);               \
                acc1[mt] = __builtin_amdgcn_mfma_f32_16x16x32_f16(            \
                    afrag[mt][ks + 1], bfr[ks + 1], acc1[mt], 0, 0, 0);       \
            }                                                                 \
        char* wb = (char*)hT[WR];                                             \
        f16x4 h4[2];                                                          \
        _Pragma("unroll")                                                     \
        for (int mt = 0; mt < 2; ++mt)                                        \
            _Pragma("unroll")                                                 \
            for (int r = 0; r < 4; ++r) {                                     \
                float s  = acc0[mt][r] + acc1[mt][r];                         \
                float ex = __builtin_amdgcn_exp2f(s);                         \
                float rc = __builtin_amdgcn_rcpf(ex + 1.0f);                  \
                h4[mt][r] = (_Float16)(1.0f - 2.0f * rc);                     \
            }                                                                 \
        if (n16 < 8) {                                                        \
            *(f16x4*)(wb + woff[0]) = h4[0];                                  \
            *(f16x4*)(wb + woff[1]) = h4[1];                                  \
        }                                                                     \
        xv = xnxt;                                                            \
        __syncthreads();                                                      \
    }

    for (int t = 0; t < SEQ; t += 2) {
        RNN_STEP(t, 0, 1);
        RNN_STEP(t + 1, 1, 0);
    }
#undef RNN_STEP

    // ---- output: out[b][c] = b_p[c] + sum_j W_ph[c][j] * h_final[j][b] ----
    // final h in hT[0]; element (n=b, k=j) at chunk (j>>3)^b
    if (tid < BN * NCLS) {
        const int b = tid / NCLS, c = tid % NCLS;
        float sum = b_p[c];
        const _Float16* hp = hT[0][b];
        for (int j = 0; j < HID; ++j) {
            const int ph = ((((j >> 3) ^ b) << 3) | (j & 7));
            sum += W_ph[c * HID + j] * (float)hp[ph];
        }
        out[(b0 + b) * NCLS + c] = sum;
    }
}

extern "C" void kernel_launch(void* const* d_in, const int* in_sizes, int n_in,
                              void* d_out, int out_size, void* d_ws, size_t ws_size,
                              hipStream_t stream) {
    const float* x    = (const float*)d_in[0];
    const float* W_hx = (const float*)d_in[1];
    const float* W_hh = (const float*)d_in[2];
    const float* W_ph = (const float*)d_in[3];
    const float* b_h  = (const float*)d_in[4];
    const float* b_p  = (const float*)d_in[5];
    float* out = (float*)d_out;

    rnn_mfma<<<dim3(2048 / BN), dim3(NT), 0, stream>>>(
        x, W_hx, W_hh, W_ph, b_h, b_p, out);
}